// Round 4
// baseline (6320.034 us; speedup 1.0000x reference)
//
#include <hip/hip_runtime.h>
#include <hip/hip_bf16.h>

#define NB    128
#define LSEQ  512
#define HIDN  512
#define EMB   256
#define DTOT  768
#define GRID_MAIN 128   // cooperative blocks; block wg owns hidden units [wg*4, wg*4+4)

typedef __attribute__((ext_vector_type(8))) short  short8;   // MFMA A/B frag (8 bf16)
typedef __attribute__((ext_vector_type(4))) float  floatx4;  // MFMA C/D frag
typedef __attribute__((ext_vector_type(4))) unsigned int uintx4;

__device__ __forceinline__ unsigned short f2bf(float f) {   // RNE
  unsigned u = __builtin_bit_cast(unsigned, f);
  unsigned r = u + 0x7fffu + ((u >> 16) & 1u);
  return (unsigned short)(r >> 16);
}
__device__ __forceinline__ unsigned bfpair(float lo, float hi) {
  unsigned a = __builtin_bit_cast(unsigned, lo) + 0x8000u;
  unsigned b = __builtin_bit_cast(unsigned, hi) + 0x8000u;
  return __builtin_amdgcn_perm(b, a, 0x07060302u);
}
__device__ __forceinline__ short8 pack8(float4 u, float4 v) {
  union { short8 s; uintx4 w; } cv;
  cv.w[0] = bfpair(u.x, u.y); cv.w[1] = bfpair(u.z, u.w);
  cv.w[2] = bfpair(v.x, v.y); cv.w[3] = bfpair(v.z, v.w);
  return cv.s;
}
__device__ __forceinline__ float sigmoid_f(float x) { return 1.f / (1.f + __expf(-x)); }
__device__ __forceinline__ float tanh_f(float x) {
  float e = __expf(2.f * x);
  return 1.f - 2.f / (e + 1.f);
}

// agent-scope coherent 16B fragment pull (2x 8B atomic loads, bypass L1/L2)
__device__ __forceinline__ short8 pull16(const unsigned long long* p) {
  union { unsigned long long u[2]; short8 s; } r;
  r.u[0] = __hip_atomic_load(p,     __ATOMIC_RELAXED, __HIP_MEMORY_SCOPE_AGENT);
  r.u[1] = __hip_atomic_load(p + 1, __ATOMIC_RELAXED, __HIP_MEMORY_SCOPE_AGENT);
  return r.s;
}

// xe[t][n][e] = bf16(E[X[n][t]][e]) — time-major, k-contiguous
__global__ void prep_x_kernel(const int* __restrict__ X, const float* __restrict__ E,
                              unsigned short* __restrict__ xe) {
  int t = blockIdx.x, n = blockIdx.y;
  int row = X[(size_t)n * LSEQ + t];
  float4 v = ((const float4*)(E + (size_t)row * EMB))[threadIdx.x];
  ushort4 o;
  o.x = f2bf(v.x); o.y = f2bf(v.y); o.z = f2bf(v.z); o.w = f2bf(v.w);
  *(ushort4*)(xe + ((size_t)t * NB + n) * EMB + threadIdx.x * 4) = o;
}

// ---- main cooperative recurrence kernel ----------------------------------
// Grid: 128 blocks x 256 thr. MFMA D = A*B: A = W^T frag (M=16 gate cols),
// B = hx frag (N=16 batch). Lane (l15,l4) acc[r] = z[gate r][unit wg*4+l4]
// [batch ...+l15] — all 4 gates of a unit in one lane, no LDS.
// h exchange: producers store normally; one release store (small wbl2)
// publishes; consumers PULL h via agent-scope atomic loads — no buffer_inv,
// L2 stays warm for xe. All waves poll distributed arrival slots.
template <bool USE_XE>
__global__ void __launch_bounds__(256, 1)
lstm_main(const int* __restrict__ X, const float* __restrict__ E,
          const unsigned short* __restrict__ xe,
          const float* __restrict__ Wi, const float* __restrict__ bi,
          const float* __restrict__ Wf, const float* __restrict__ bf_,
          const float* __restrict__ Wo, const float* __restrict__ bo,
          const float* __restrict__ Wh, const float* __restrict__ bh,
          float* __restrict__ out, unsigned short* __restrict__ hb,
          int* __restrict__ arrive) {
  const int wg   = blockIdx.x;
  const int tid  = threadIdx.x;
  const int lane = tid & 63;
  const int wv   = tid >> 6;
  const int l15  = lane & 15;
  const int l4   = lane >> 4;
  const int mbase = wv * 32;

  // --- W fragments (A operand), loaded once into 96 VGPRs ---
  const int cg = wg * 16 + l15;          // gate column c = j*4+g
  const int jcol = cg >> 2, g = cg & 3;
  const float* Wg = (g == 0) ? Wi : (g == 1) ? Wf : (g == 2) ? Wo : Wh;
  short8 bfrag[24];
#pragma unroll
  for (int kt = 0; kt < 24; ++kt) {
    union { short8 s; unsigned short us[8]; } cv;
#pragma unroll
    for (int e = 0; e < 8; ++e) {
      int k = kt * 32 + l4 * 8 + e;
      cv.us[e] = f2bf(Wg[(size_t)k * HIDN + jcol]);
    }
    bfrag[kt] = cv.s;
  }

  const int jglob = wg * 4 + l4;
  const float bI = bi[jglob], bF = bf_[jglob], bO = bo[jglob], bH = bh[jglob];
  float c0 = 0.f, c1 = 0.f;

  // --- x fragments for t=0 ---
  short8 xf[8][2];
#pragma unroll
  for (int q = 0; q < 2; ++q) {
    int n = mbase + q * 16 + l15;
    if (USE_XE) {
      const unsigned short* xr = xe + (size_t)n * EMB + l4 * 8;
#pragma unroll
      for (int kt = 0; kt < 8; ++kt) xf[kt][q] = *(const short8*)(xr + kt * 32);
    } else {
      int idx = X[(size_t)n * LSEQ + 0];
      const float* er = E + (size_t)idx * EMB + l4 * 8;
#pragma unroll
      for (int kt = 0; kt < 8; ++kt) {
        float4 u = *(const float4*)(er + kt * 32);
        float4 v = *(const float4*)(er + kt * 32 + 4);
        xf[kt][q] = pack8(u, v);
      }
    }
  }

  unsigned short* hcur = hb;                       // zeroed by host memset: h_0 = 0
  unsigned short* hnxt = hb + (size_t)NB * HIDN;

  // acc starts with the x-GEMM contribution for step 0
  floatx4 acc0 = {0.f, 0.f, 0.f, 0.f};
  floatx4 acc1 = {0.f, 0.f, 0.f, 0.f};
#pragma unroll
  for (int kt = 0; kt < 8; ++kt) {
    acc0 = __builtin_amdgcn_mfma_f32_16x16x32_bf16(bfrag[16 + kt], xf[kt][0], acc0, 0, 0, 0);
    acc1 = __builtin_amdgcn_mfma_f32_16x16x32_bf16(bfrag[16 + kt], xf[kt][1], acc1, 0, 0, 0);
  }

  for (int t = 0; t < LSEQ; ++t) {
    // --- pull h fragments via agent-coherent loads (no cache invalidate) ---
    const unsigned long long* h0p =
        (const unsigned long long*)(hcur + (size_t)(mbase + l15) * HIDN) + l4 * 2;
    const unsigned long long* h1p =
        (const unsigned long long*)(hcur + (size_t)(mbase + 16 + l15) * HIDN) + l4 * 2;
    short8 hf0[16], hf1[16];
#pragma unroll
    for (int kt = 0; kt < 16; ++kt) hf0[kt] = pull16(h0p + kt * 8);
#pragma unroll
    for (int kt = 0; kt < 16; ++kt) hf1[kt] = pull16(h1p + kt * 8);

#pragma unroll
    for (int kt = 0; kt < 16; ++kt) {
      acc0 = __builtin_amdgcn_mfma_f32_16x16x32_bf16(bfrag[kt], hf0[kt], acc0, 0, 0, 0);
      acc1 = __builtin_amdgcn_mfma_f32_16x16x32_bf16(bfrag[kt], hf1[kt], acc1, 0, 0, 0);
    }

    // --- gates ---
#pragma unroll
    for (int q = 0; q < 2; ++q) {
      floatx4 z = q ? acc1 : acc0;
      float ig = sigmoid_f(z[0] + bI);
      float fg = sigmoid_f(z[1] + bF);
      float og = sigmoid_f(z[2] + bO);
      float gg = tanh_f(z[3] + bH);
      float cs = q ? c1 : c0;
      cs = fg * cs + ig * gg;
      if (q) c1 = cs; else c0 = cs;
      float h = og * tanh_f(cs);
      int n = mbase + q * 16 + l15;
      hnxt[(size_t)n * HIDN + jglob] = f2bf(h);
      if (t == LSEQ - 1) out[(size_t)n * HIDN + jglob] = h;
    }

    if (t == LSEQ - 1) break;

    // --- prefetch x fragments for t+1 ---
#pragma unroll
    for (int q = 0; q < 2; ++q) {
      int n = mbase + q * 16 + l15;
      if (USE_XE) {
        const unsigned short* xr = xe + ((size_t)(t + 1) * NB + n) * EMB + l4 * 8;
#pragma unroll
        for (int kt = 0; kt < 8; ++kt) xf[kt][q] = *(const short8*)(xr + kt * 32);
      } else {
        int idx = X[(size_t)n * LSEQ + t + 1];
        const float* er = E + (size_t)idx * EMB + l4 * 8;
#pragma unroll
        for (int kt = 0; kt < 8; ++kt) {
          float4 u = *(const float4*)(er + kt * 32);
          float4 v = *(const float4*)(er + kt * 32 + 4);
          xf[kt][q] = pack8(u, v);
        }
      }
    }

    { unsigned short* tmp = hcur; hcur = hnxt; hnxt = tmp; }

    const int gen = t + 1;
    // all waves' h stores drained by the vmcnt(0) implied in __syncthreads
    __syncthreads();
    if (tid == 0)   // release: waitcnt + small wbl2 (only ~1KB dirty) + flag store
      __hip_atomic_store(&arrive[wg * 16], gen, __ATOMIC_RELEASE,
                         __HIP_MEMORY_SCOPE_AGENT);

    // overlap the wait: next step's x-GEMM (registers only)
    acc0 = floatx4{0.f, 0.f, 0.f, 0.f};
    acc1 = floatx4{0.f, 0.f, 0.f, 0.f};
#pragma unroll
    for (int kt = 0; kt < 8; ++kt) {
      acc0 = __builtin_amdgcn_mfma_f32_16x16x32_bf16(bfrag[16 + kt], xf[kt][0], acc0, 0, 0, 0);
      acc1 = __builtin_amdgcn_mfma_f32_16x16x32_bf16(bfrag[16 + kt], xf[kt][1], acc1, 0, 0, 0);
    }

    // every wave polls all 128 slots (2 per lane) — no second __syncthreads
    while (__hip_atomic_load(&arrive[lane * 16], __ATOMIC_RELAXED,
                             __HIP_MEMORY_SCOPE_AGENT) < gen)
      __builtin_amdgcn_s_sleep(1);
    while (__hip_atomic_load(&arrive[(lane + 64) * 16], __ATOMIC_RELAXED,
                             __HIP_MEMORY_SCOPE_AGENT) < gen)
      __builtin_amdgcn_s_sleep(1);
    __atomic_signal_fence(__ATOMIC_ACQUIRE);  // compiler barrier only
  }
}

// ws layout: [0, 8192) arrival slots (128 x 64B), [8192, +262144) h double
// buffer, then (optional, if ws_size permits) xe bf16 time-major (33.5 MB).
extern "C" void kernel_launch(void* const* d_in, const int* in_sizes, int n_in,
                              void* d_out, int out_size, void* d_ws, size_t ws_size,
                              hipStream_t stream) {
  const int*   X  = (const int*)d_in[0];
  const float* E  = (const float*)d_in[1];
  const float* Wi = (const float*)d_in[2];
  const float* bi = (const float*)d_in[3];
  const float* Wf = (const float*)d_in[4];
  const float* bf = (const float*)d_in[5];
  const float* Wo = (const float*)d_in[6];
  const float* bo = (const float*)d_in[7];
  const float* Wh = (const float*)d_in[8];
  const float* bh = (const float*)d_in[9];
  float* out = (float*)d_out;

  char* ws = (char*)d_ws;
  int* arrive = (int*)ws;
  unsigned short* hb = (unsigned short*)(ws + 8192);
  const size_t xe_off = 8192 + 2 * (size_t)NB * HIDN * sizeof(unsigned short);
  const size_t xe_bytes = (size_t)LSEQ * NB * EMB * sizeof(unsigned short);
  const bool use_xe = ws_size >= xe_off + xe_bytes;
  unsigned short* xe = use_xe ? (unsigned short*)(ws + xe_off) : nullptr;

  hipMemsetAsync(ws, 0, xe_off, stream);  // zero barrier slots + h_0

  if (use_xe)
    prep_x_kernel<<<dim3(LSEQ, NB), dim3(64), 0, stream>>>(X, E, xe);

  void* args[] = { (void*)&X, (void*)&E, (void*)&xe,
                   (void*)&Wi, (void*)&bi, (void*)&Wf, (void*)&bf,
                   (void*)&Wo, (void*)&bo, (void*)&Wh, (void*)&bh,
                   (void*)&out, (void*)&hb, (void*)&arrive };
  if (use_xe)
    hipLaunchCooperativeKernel(reinterpret_cast<void*>(lstm_main<true>),
                               dim3(GRID_MAIN), dim3(256), args, 0, stream);
  else
    hipLaunchCooperativeKernel(reinterpret_cast<void*>(lstm_main<false>),
                               dim3(GRID_MAIN), dim3(256), args, 0, stream);
}

// Round 5
// 5687.891 us; speedup vs baseline: 1.1111x; 1.1111x over previous
//
#include <hip/hip_runtime.h>
#include <hip/hip_bf16.h>

#define NB    128
#define LSEQ  512
#define HIDN  512
#define EMB   256
#define DTOT  768
#define GRID_MAIN 128   // cooperative blocks; block wg owns hidden units [wg*4, wg*4+4)

typedef __attribute__((ext_vector_type(8))) short  short8;   // MFMA A/B frag (8 bf16)
typedef __attribute__((ext_vector_type(4))) float  floatx4;  // MFMA C/D frag
typedef __attribute__((ext_vector_type(4))) unsigned int uintx4;

__device__ __forceinline__ unsigned short f2bf(float f) {   // RNE
  unsigned u = __builtin_bit_cast(unsigned, f);
  unsigned r = u + 0x7fffu + ((u >> 16) & 1u);
  return (unsigned short)(r >> 16);
}
__device__ __forceinline__ unsigned bfpair(float lo, float hi) {
  unsigned a = __builtin_bit_cast(unsigned, lo) + 0x8000u;
  unsigned b = __builtin_bit_cast(unsigned, hi) + 0x8000u;
  return __builtin_amdgcn_perm(b, a, 0x07060302u);
}
__device__ __forceinline__ short8 pack8(float4 u, float4 v) {
  union { short8 s; uintx4 w; } cv;
  cv.w[0] = bfpair(u.x, u.y); cv.w[1] = bfpair(u.z, u.w);
  cv.w[2] = bfpair(v.x, v.y); cv.w[3] = bfpair(v.z, v.w);
  return cv.s;
}
__device__ __forceinline__ float sigmoid_f(float x) { return 1.f / (1.f + __expf(-x)); }
__device__ __forceinline__ float tanh_f(float x) {
  float e = __expf(2.f * x);
  return 1.f - 2.f / (e + 1.f);
}

// agent-scope coherent 16B fragment pull (2x 8B atomic loads — read L3
// coherence point directly; no cache-invalidate needed)
__device__ __forceinline__ short8 pull16(const unsigned long long* p) {
  union { unsigned long long u[2]; short8 s; } r;
  r.u[0] = __hip_atomic_load(p,     __ATOMIC_RELAXED, __HIP_MEMORY_SCOPE_AGENT);
  r.u[1] = __hip_atomic_load(p + 1, __ATOMIC_RELAXED, __HIP_MEMORY_SCOPE_AGENT);
  return r.s;
}

// xe[t][n][e] = bf16(E[X[n][t]][e]) — time-major, k-contiguous
__global__ void prep_x_kernel(const int* __restrict__ X, const float* __restrict__ E,
                              unsigned short* __restrict__ xe) {
  int t = blockIdx.x, n = blockIdx.y;
  int row = X[(size_t)n * LSEQ + t];
  float4 v = ((const float4*)(E + (size_t)row * EMB))[threadIdx.x];
  ushort4 o;
  o.x = f2bf(v.x); o.y = f2bf(v.y); o.z = f2bf(v.z); o.w = f2bf(v.w);
  *(ushort4*)(xe + ((size_t)t * NB + n) * EMB + threadIdx.x * 4) = o;
}

// ---- main cooperative recurrence kernel ----------------------------------
// ZERO cache-maintenance steady state: h producers write agent-scope
// write-through atomic stores (no dirty L2); __syncthreads' vmcnt(0) drain
// orders them before a RELAXED flag store (no release -> no buffer_wbl2);
// consumers pull h with agent-scope atomic loads (no buffer_inv).
template <bool USE_XE>
__global__ void __launch_bounds__(256, 1)
lstm_main(const int* __restrict__ X, const float* __restrict__ E,
          const unsigned short* __restrict__ xe,
          const float* __restrict__ Wi, const float* __restrict__ bi,
          const float* __restrict__ Wf, const float* __restrict__ bf_,
          const float* __restrict__ Wo, const float* __restrict__ bo,
          const float* __restrict__ Wh, const float* __restrict__ bh,
          float* __restrict__ out, unsigned short* __restrict__ hb,
          int* __restrict__ arrive) {
  const int wg   = blockIdx.x;
  const int tid  = threadIdx.x;
  const int lane = tid & 63;
  const int wv   = tid >> 6;
  const int l15  = lane & 15;
  const int l4   = lane >> 4;
  const int mbase = wv * 32;

  // --- W fragments (A operand), loaded once into 96 VGPRs ---
  const int cg = wg * 16 + l15;          // gate column c = j*4+g
  const int jcol = cg >> 2, g = cg & 3;
  const float* Wg = (g == 0) ? Wi : (g == 1) ? Wf : (g == 2) ? Wo : Wh;
  short8 bfrag[24];
#pragma unroll
  for (int kt = 0; kt < 24; ++kt) {
    union { short8 s; unsigned short us[8]; } cv;
#pragma unroll
    for (int e = 0; e < 8; ++e) {
      int k = kt * 32 + l4 * 8 + e;
      cv.us[e] = f2bf(Wg[(size_t)k * HIDN + jcol]);
    }
    bfrag[kt] = cv.s;
  }

  const int jglob = wg * 4 + l4;
  const float bI = bi[jglob], bF = bf_[jglob], bO = bo[jglob], bH = bh[jglob];
  float c0 = 0.f, c1 = 0.f;

  // --- x fragments for t=0 ---
  short8 xf[8][2];
#pragma unroll
  for (int q = 0; q < 2; ++q) {
    int n = mbase + q * 16 + l15;
    if (USE_XE) {
      const unsigned short* xr = xe + (size_t)n * EMB + l4 * 8;
#pragma unroll
      for (int kt = 0; kt < 8; ++kt) xf[kt][q] = *(const short8*)(xr + kt * 32);
    } else {
      int idx = X[(size_t)n * LSEQ + 0];
      const float* er = E + (size_t)idx * EMB + l4 * 8;
#pragma unroll
      for (int kt = 0; kt < 8; ++kt) {
        float4 u = *(const float4*)(er + kt * 32);
        float4 v = *(const float4*)(er + kt * 32 + 4);
        xf[kt][q] = pack8(u, v);
      }
    }
  }

  unsigned short* hcur = hb;                       // zeroed by host memset: h_0 = 0
  unsigned short* hnxt = hb + (size_t)NB * HIDN;

  // acc starts with the x-GEMM contribution for step 0
  floatx4 acc0 = {0.f, 0.f, 0.f, 0.f};
  floatx4 acc1 = {0.f, 0.f, 0.f, 0.f};
#pragma unroll
  for (int kt = 0; kt < 8; ++kt) {
    acc0 = __builtin_amdgcn_mfma_f32_16x16x32_bf16(bfrag[16 + kt], xf[kt][0], acc0, 0, 0, 0);
    acc1 = __builtin_amdgcn_mfma_f32_16x16x32_bf16(bfrag[16 + kt], xf[kt][1], acc1, 0, 0, 0);
  }

  const bool storer = ((l4 & 1) == 0);   // even-l4 lanes store 4B pairs

  for (int t = 0; t < LSEQ; ++t) {
    // --- pull h fragments via agent-coherent loads ---
    const unsigned long long* h0p =
        (const unsigned long long*)(hcur + (size_t)(mbase + l15) * HIDN) + l4 * 2;
    const unsigned long long* h1p =
        (const unsigned long long*)(hcur + (size_t)(mbase + 16 + l15) * HIDN) + l4 * 2;
    short8 hf0[16], hf1[16];
#pragma unroll
    for (int kt = 0; kt < 16; ++kt) hf0[kt] = pull16(h0p + kt * 8);
#pragma unroll
    for (int kt = 0; kt < 16; ++kt) hf1[kt] = pull16(h1p + kt * 8);

#pragma unroll
    for (int kt = 0; kt < 16; ++kt) {
      acc0 = __builtin_amdgcn_mfma_f32_16x16x32_bf16(bfrag[kt], hf0[kt], acc0, 0, 0, 0);
      acc1 = __builtin_amdgcn_mfma_f32_16x16x32_bf16(bfrag[kt], hf1[kt], acc1, 0, 0, 0);
    }

    // --- gates: lane (l15,l4) q -> h[n = mbase+q*16+l15][j = wg*4+l4] ---
    float hq[2];
#pragma unroll
    for (int q = 0; q < 2; ++q) {
      floatx4 z = q ? acc1 : acc0;
      float ig = sigmoid_f(z[0] + bI);
      float fg = sigmoid_f(z[1] + bF);
      float og = sigmoid_f(z[2] + bO);
      float gg = tanh_f(z[3] + bH);
      float cs = q ? c1 : c0;
      cs = fg * cs + ig * gg;
      if (q) c1 = cs; else c0 = cs;
      hq[q] = og * tanh_f(cs);
    }

    // pack (q0,q1) as one word, swap with lane^16 partner (l4 xor 1),
    // even-l4 lanes issue two 4B agent-scope write-through stores
    unsigned w  = (unsigned)f2bf(hq[0]) | ((unsigned)f2bf(hq[1]) << 16);
    unsigned wp = (unsigned)__builtin_amdgcn_ds_swizzle((int)w, 0x401F); // xor 16
    if (storer) {
      unsigned v0 = __builtin_amdgcn_perm(wp, w, 0x05040100u); // [own q0, partner q0]
      unsigned v1 = __builtin_amdgcn_perm(wp, w, 0x07060302u); // [own q1, partner q1]
      unsigned* p0 = (unsigned*)(hnxt + (size_t)(mbase + l15) * HIDN + jglob);
      unsigned* p1 = (unsigned*)(hnxt + (size_t)(mbase + 16 + l15) * HIDN + jglob);
      __hip_atomic_store(p0, v0, __ATOMIC_RELAXED, __HIP_MEMORY_SCOPE_AGENT);
      __hip_atomic_store(p1, v1, __ATOMIC_RELAXED, __HIP_MEMORY_SCOPE_AGENT);
    }

    if (t == LSEQ - 1) {
#pragma unroll
      for (int q = 0; q < 2; ++q)
        out[(size_t)(mbase + q * 16 + l15) * HIDN + jglob] = hq[q];
      break;
    }

    // --- prefetch x fragments for t+1 (cached loads, L2 stays warm) ---
#pragma unroll
    for (int q = 0; q < 2; ++q) {
      int n = mbase + q * 16 + l15;
      if (USE_XE) {
        const unsigned short* xr = xe + ((size_t)(t + 1) * NB + n) * EMB + l4 * 8;
#pragma unroll
        for (int kt = 0; kt < 8; ++kt) xf[kt][q] = *(const short8*)(xr + kt * 32);
      } else {
        int idx = X[(size_t)n * LSEQ + t + 1];
        const float* er = E + (size_t)idx * EMB + l4 * 8;
#pragma unroll
        for (int kt = 0; kt < 8; ++kt) {
          float4 u = *(const float4*)(er + kt * 32);
          float4 v = *(const float4*)(er + kt * 32 + 4);
          xf[kt][q] = pack8(u, v);
        }
      }
    }

    { unsigned short* tmp = hcur; hcur = hnxt; hnxt = tmp; }

    const int gen = t + 1;
    // __syncthreads drains vmcnt(0): all h stores are at the L3 coherence
    // point (write-through) before the flag below is issued -> relaxed is safe
    __syncthreads();
    if (tid == 0)
      __hip_atomic_store(&arrive[wg * 16], gen, __ATOMIC_RELAXED,
                         __HIP_MEMORY_SCOPE_AGENT);

    // overlap the wait: next step's x-GEMM (registers only)
    acc0 = floatx4{0.f, 0.f, 0.f, 0.f};
    acc1 = floatx4{0.f, 0.f, 0.f, 0.f};
#pragma unroll
    for (int kt = 0; kt < 8; ++kt) {
      acc0 = __builtin_amdgcn_mfma_f32_16x16x32_bf16(bfrag[16 + kt], xf[kt][0], acc0, 0, 0, 0);
      acc1 = __builtin_amdgcn_mfma_f32_16x16x32_bf16(bfrag[16 + kt], xf[kt][1], acc1, 0, 0, 0);
    }

    // every wave polls all 128 slots (2 per lane)
    while (__hip_atomic_load(&arrive[lane * 16], __ATOMIC_RELAXED,
                             __HIP_MEMORY_SCOPE_AGENT) < gen) {}
    while (__hip_atomic_load(&arrive[(lane + 64) * 16], __ATOMIC_RELAXED,
                             __HIP_MEMORY_SCOPE_AGENT) < gen) {}
    __atomic_signal_fence(__ATOMIC_ACQUIRE);  // compiler barrier only
  }
}

// ws layout: [0, 8192) arrival slots (128 x 64B), [8192, +262144) h double
// buffer, then (optional, if ws_size permits) xe bf16 time-major (33.5 MB).
extern "C" void kernel_launch(void* const* d_in, const int* in_sizes, int n_in,
                              void* d_out, int out_size, void* d_ws, size_t ws_size,
                              hipStream_t stream) {
  const int*   X  = (const int*)d_in[0];
  const float* E  = (const float*)d_in[1];
  const float* Wi = (const float*)d_in[2];
  const float* bi = (const float*)d_in[3];
  const float* Wf = (const float*)d_in[4];
  const float* bf = (const float*)d_in[5];
  const float* Wo = (const float*)d_in[6];
  const float* bo = (const float*)d_in[7];
  const float* Wh = (const float*)d_in[8];
  const float* bh = (const float*)d_in[9];
  float* out = (float*)d_out;

  char* ws = (char*)d_ws;
  int* arrive = (int*)ws;
  unsigned short* hb = (unsigned short*)(ws + 8192);
  const size_t xe_off = 8192 + 2 * (size_t)NB * HIDN * sizeof(unsigned short);
  const size_t xe_bytes = (size_t)LSEQ * NB * EMB * sizeof(unsigned short);
  const bool use_xe = ws_size >= xe_off + xe_bytes;
  unsigned short* xe = use_xe ? (unsigned short*)(ws + xe_off) : nullptr;

  hipMemsetAsync(ws, 0, xe_off, stream);  // zero barrier slots + h_0

  if (use_xe)
    prep_x_kernel<<<dim3(LSEQ, NB), dim3(64), 0, stream>>>(X, E, xe);

  void* args[] = { (void*)&X, (void*)&E, (void*)&xe,
                   (void*)&Wi, (void*)&bi, (void*)&Wf, (void*)&bf,
                   (void*)&Wo, (void*)&bo, (void*)&Wh, (void*)&bh,
                   (void*)&out, (void*)&hb, (void*)&arrive };
  if (use_xe)
    hipLaunchCooperativeKernel(reinterpret_cast<void*>(lstm_main<true>),
                               dim3(GRID_MAIN), dim3(256), args, 0, stream);
  else
    hipLaunchCooperativeKernel(reinterpret_cast<void*>(lstm_main<false>),
                               dim3(GRID_MAIN), dim3(256), args, 0, stream);
}

// Round 6
// 5573.918 us; speedup vs baseline: 1.1339x; 1.0204x over previous
//
#include <hip/hip_runtime.h>
#include <hip/hip_bf16.h>

#define NB    128
#define LSEQ  512
#define HIDN  512
#define EMB   256
#define DTOT  768
#define GRID_MAIN 128   // cooperative blocks; block wg owns hidden units [wg*4, wg*4+4)

typedef __attribute__((ext_vector_type(8))) short  short8;   // MFMA A/B frag (8 bf16)
typedef __attribute__((ext_vector_type(4))) float  floatx4;  // MFMA C/D frag
typedef __attribute__((ext_vector_type(4))) unsigned int uintx4;

__device__ __forceinline__ unsigned short f2bf(float f) {   // RNE
  unsigned u = __builtin_bit_cast(unsigned, f);
  unsigned r = u + 0x7fffu + ((u >> 16) & 1u);
  return (unsigned short)(r >> 16);
}
__device__ __forceinline__ unsigned bfpair(float lo, float hi) {
  unsigned a = __builtin_bit_cast(unsigned, lo) + 0x8000u;
  unsigned b = __builtin_bit_cast(unsigned, hi) + 0x8000u;
  return __builtin_amdgcn_perm(b, a, 0x07060302u);
}
__device__ __forceinline__ short8 pack8(float4 u, float4 v) {
  union { short8 s; uintx4 w; } cv;
  cv.w[0] = bfpair(u.x, u.y); cv.w[1] = bfpair(u.z, u.w);
  cv.w[2] = bfpair(v.x, v.y); cv.w[3] = bfpair(v.z, v.w);
  return cv.s;
}
__device__ __forceinline__ float sigmoid_f(float x) { return 1.f / (1.f + __expf(-x)); }
__device__ __forceinline__ float tanh_f(float x) {
  float e = __expf(2.f * x);
  return 1.f - 2.f / (e + 1.f);
}

// agent-scope coherent 16B fragment pull (2x 8B atomic loads — read the L3
// coherence point directly; no cache-invalidate needed)
__device__ __forceinline__ short8 pull16(const unsigned long long* p) {
  union { unsigned long long u[2]; short8 s; } r;
  r.u[0] = __hip_atomic_load(p,     __ATOMIC_RELAXED, __HIP_MEMORY_SCOPE_AGENT);
  r.u[1] = __hip_atomic_load(p + 1, __ATOMIC_RELAXED, __HIP_MEMORY_SCOPE_AGENT);
  return r.s;
}

// xe[t][n][e] = bf16(E[X[n][t]][e]) — time-major, k-contiguous
__global__ void prep_x_kernel(const int* __restrict__ X, const float* __restrict__ E,
                              unsigned short* __restrict__ xe) {
  int t = blockIdx.x, n = blockIdx.y;
  int row = X[(size_t)n * LSEQ + t];
  float4 v = ((const float4*)(E + (size_t)row * EMB))[threadIdx.x];
  ushort4 o;
  o.x = f2bf(v.x); o.y = f2bf(v.y); o.z = f2bf(v.z); o.w = f2bf(v.w);
  *(ushort4*)(xe + ((size_t)t * NB + n) * EMB + threadIdx.x * 4) = o;
}

// ---- main cooperative recurrence kernel ----------------------------------
// Critical chain per step: poll detect -> pull h (L3) -> 32 MFMA -> gates ->
// 2 h-stores (sc1 write-through) -> __syncthreads (drains ONLY those stores)
// -> flag. xe prefetch + x-GEMM for t+1 run AFTER the flag, overlapping
// other blocks' arrival. Zero cache-maintenance ops in the loop.
template <bool USE_XE>
__global__ void __launch_bounds__(256, 1)
lstm_main(const int* __restrict__ X, const float* __restrict__ E,
          const unsigned short* __restrict__ xe,
          const float* __restrict__ Wi, const float* __restrict__ bi,
          const float* __restrict__ Wf, const float* __restrict__ bf_,
          const float* __restrict__ Wo, const float* __restrict__ bo,
          const float* __restrict__ Wh, const float* __restrict__ bh,
          float* __restrict__ out, unsigned short* __restrict__ hb,
          int* __restrict__ arrive) {
  const int wg   = blockIdx.x;
  const int tid  = threadIdx.x;
  const int lane = tid & 63;
  const int wv   = tid >> 6;
  const int l15  = lane & 15;
  const int l4   = lane >> 4;
  const int mbase = wv * 32;

  // --- W fragments (A operand), loaded once into 96 VGPRs ---
  const int cg = wg * 16 + l15;          // gate column c = j*4+g
  const int jcol = cg >> 2, g = cg & 3;
  const float* Wg = (g == 0) ? Wi : (g == 1) ? Wf : (g == 2) ? Wo : Wh;
  short8 bfrag[24];
#pragma unroll
  for (int kt = 0; kt < 24; ++kt) {
    union { short8 s; unsigned short us[8]; } cv;
#pragma unroll
    for (int e = 0; e < 8; ++e) {
      int k = kt * 32 + l4 * 8 + e;
      cv.us[e] = f2bf(Wg[(size_t)k * HIDN + jcol]);
    }
    bfrag[kt] = cv.s;
  }

  const int jglob = wg * 4 + l4;
  const float bI = bi[jglob], bF = bf_[jglob], bO = bo[jglob], bH = bh[jglob];
  float c0 = 0.f, c1 = 0.f;

  // --- x fragments for t=0 ---
  short8 xf[8][2];
#pragma unroll
  for (int q = 0; q < 2; ++q) {
    int n = mbase + q * 16 + l15;
    if (USE_XE) {
      const unsigned short* xr = xe + (size_t)n * EMB + l4 * 8;
#pragma unroll
      for (int kt = 0; kt < 8; ++kt) xf[kt][q] = *(const short8*)(xr + kt * 32);
    } else {
      int idx = X[(size_t)n * LSEQ + 0];
      const float* er = E + (size_t)idx * EMB + l4 * 8;
#pragma unroll
      for (int kt = 0; kt < 8; ++kt) {
        float4 u = *(const float4*)(er + kt * 32);
        float4 v = *(const float4*)(er + kt * 32 + 4);
        xf[kt][q] = pack8(u, v);
      }
    }
  }

  unsigned short* hcur = hb;                       // zeroed by host memset: h_0 = 0
  unsigned short* hnxt = hb + (size_t)NB * HIDN;

  // acc starts with the x-GEMM contribution for step 0
  floatx4 acc0 = {0.f, 0.f, 0.f, 0.f};
  floatx4 acc1 = {0.f, 0.f, 0.f, 0.f};
#pragma unroll
  for (int kt = 0; kt < 8; ++kt) {
    acc0 = __builtin_amdgcn_mfma_f32_16x16x32_bf16(bfrag[16 + kt], xf[kt][0], acc0, 0, 0, 0);
    acc1 = __builtin_amdgcn_mfma_f32_16x16x32_bf16(bfrag[16 + kt], xf[kt][1], acc1, 0, 0, 0);
  }

  const bool storer = ((l4 & 1) == 0);   // even-l4 lanes store 4B pairs

  for (int t = 0; t < LSEQ; ++t) {
    // --- pull h fragments via agent-coherent loads ---
    const unsigned long long* h0p =
        (const unsigned long long*)(hcur + (size_t)(mbase + l15) * HIDN) + l4 * 2;
    const unsigned long long* h1p =
        (const unsigned long long*)(hcur + (size_t)(mbase + 16 + l15) * HIDN) + l4 * 2;
    short8 hf0[16], hf1[16];
#pragma unroll
    for (int kt = 0; kt < 16; ++kt) hf0[kt] = pull16(h0p + kt * 8);
#pragma unroll
    for (int kt = 0; kt < 16; ++kt) hf1[kt] = pull16(h1p + kt * 8);

#pragma unroll
    for (int kt = 0; kt < 16; ++kt) {
      acc0 = __builtin_amdgcn_mfma_f32_16x16x32_bf16(bfrag[kt], hf0[kt], acc0, 0, 0, 0);
      acc1 = __builtin_amdgcn_mfma_f32_16x16x32_bf16(bfrag[kt], hf1[kt], acc1, 0, 0, 0);
    }

    // --- gates: lane (l15,l4) q -> h[n = mbase+q*16+l15][j = wg*4+l4] ---
    float hq[2];
#pragma unroll
    for (int q = 0; q < 2; ++q) {
      floatx4 z = q ? acc1 : acc0;
      float ig = sigmoid_f(z[0] + bI);
      float fg = sigmoid_f(z[1] + bF);
      float og = sigmoid_f(z[2] + bO);
      float gg = tanh_f(z[3] + bH);
      float cs = q ? c1 : c0;
      cs = fg * cs + ig * gg;
      if (q) c1 = cs; else c0 = cs;
      hq[q] = og * tanh_f(cs);
    }

    // pack (q0,q1), swap with lane^16 partner, even-l4 lanes store 4B pairs
    unsigned w  = (unsigned)f2bf(hq[0]) | ((unsigned)f2bf(hq[1]) << 16);
    unsigned wp = (unsigned)__builtin_amdgcn_ds_swizzle((int)w, 0x401F); // xor 16
    if (storer) {
      unsigned v0 = __builtin_amdgcn_perm(wp, w, 0x05040100u); // [own q0, partner q0]
      unsigned v1 = __builtin_amdgcn_perm(wp, w, 0x07060302u); // [own q1, partner q1]
      unsigned* p0 = (unsigned*)(hnxt + (size_t)(mbase + l15) * HIDN + jglob);
      unsigned* p1 = (unsigned*)(hnxt + (size_t)(mbase + 16 + l15) * HIDN + jglob);
      __hip_atomic_store(p0, v0, __ATOMIC_RELAXED, __HIP_MEMORY_SCOPE_AGENT);
      __hip_atomic_store(p1, v1, __ATOMIC_RELAXED, __HIP_MEMORY_SCOPE_AGENT);
    }

    if (t == LSEQ - 1) {
#pragma unroll
      for (int q = 0; q < 2; ++q)
        out[(size_t)(mbase + q * 16 + l15) * HIDN + jglob] = hq[q];
      break;
    }

    { unsigned short* tmp = hcur; hcur = hnxt; hnxt = tmp; }

    const int gen = t + 1;
    // __syncthreads drains vmcnt(0): ONLY the 2 h stores are outstanding
    // here (xe prefetch moved below) -> flag goes out fast.
    __syncthreads();
    if (tid == 0)
      __hip_atomic_store(&arrive[wg * 16], gen, __ATOMIC_RELAXED,
                         __HIP_MEMORY_SCOPE_AGENT);

    // --- off-chain: prefetch x for t+1 and run its x-GEMM while others arrive
#pragma unroll
    for (int q = 0; q < 2; ++q) {
      int n = mbase + q * 16 + l15;
      if (USE_XE) {
        const unsigned short* xr = xe + ((size_t)(t + 1) * NB + n) * EMB + l4 * 8;
#pragma unroll
        for (int kt = 0; kt < 8; ++kt) xf[kt][q] = *(const short8*)(xr + kt * 32);
      } else {
        int idx = X[(size_t)n * LSEQ + t + 1];
        const float* er = E + (size_t)idx * EMB + l4 * 8;
#pragma unroll
        for (int kt = 0; kt < 8; ++kt) {
          float4 u = *(const float4*)(er + kt * 32);
          float4 v = *(const float4*)(er + kt * 32 + 4);
          xf[kt][q] = pack8(u, v);
        }
      }
    }
    acc0 = floatx4{0.f, 0.f, 0.f, 0.f};
    acc1 = floatx4{0.f, 0.f, 0.f, 0.f};
#pragma unroll
    for (int kt = 0; kt < 8; ++kt) {
      acc0 = __builtin_amdgcn_mfma_f32_16x16x32_bf16(bfrag[16 + kt], xf[kt][0], acc0, 0, 0, 0);
      acc1 = __builtin_amdgcn_mfma_f32_16x16x32_bf16(bfrag[16 + kt], xf[kt][1], acc1, 0, 0, 0);
    }

    // combined poll: both slot loads issued per iteration (one round-trip)
    {
      const int* sA = &arrive[lane * 16];
      const int* sB = &arrive[(lane + 64) * 16];
      int va, vb;
      do {
        va = __hip_atomic_load(sA, __ATOMIC_RELAXED, __HIP_MEMORY_SCOPE_AGENT);
        vb = __hip_atomic_load(sB, __ATOMIC_RELAXED, __HIP_MEMORY_SCOPE_AGENT);
      } while (va < gen || vb < gen);
    }
    __atomic_signal_fence(__ATOMIC_ACQUIRE);  // compiler barrier only
  }
}

// ws layout: [0, 8192) arrival slots (128 x 64B), [8192, +262144) h double
// buffer, then (optional, if ws_size permits) xe bf16 time-major (33.5 MB).
extern "C" void kernel_launch(void* const* d_in, const int* in_sizes, int n_in,
                              void* d_out, int out_size, void* d_ws, size_t ws_size,
                              hipStream_t stream) {
  const int*   X  = (const int*)d_in[0];
  const float* E  = (const float*)d_in[1];
  const float* Wi = (const float*)d_in[2];
  const float* bi = (const float*)d_in[3];
  const float* Wf = (const float*)d_in[4];
  const float* bf = (const float*)d_in[5];
  const float* Wo = (const float*)d_in[6];
  const float* bo = (const float*)d_in[7];
  const float* Wh = (const float*)d_in[8];
  const float* bh = (const float*)d_in[9];
  float* out = (float*)d_out;

  char* ws = (char*)d_ws;
  int* arrive = (int*)ws;
  unsigned short* hb = (unsigned short*)(ws + 8192);
  const size_t xe_off = 8192 + 2 * (size_t)NB * HIDN * sizeof(unsigned short);
  const size_t xe_bytes = (size_t)LSEQ * NB * EMB * sizeof(unsigned short);
  const bool use_xe = ws_size >= xe_off + xe_bytes;
  unsigned short* xe = use_xe ? (unsigned short*)(ws + xe_off) : nullptr;

  hipMemsetAsync(ws, 0, xe_off, stream);  // zero barrier slots + h_0

  if (use_xe)
    prep_x_kernel<<<dim3(LSEQ, NB), dim3(64), 0, stream>>>(X, E, xe);

  void* args[] = { (void*)&X, (void*)&E, (void*)&xe,
                   (void*)&Wi, (void*)&bi, (void*)&Wf, (void*)&bf,
                   (void*)&Wo, (void*)&bo, (void*)&Wh, (void*)&bh,
                   (void*)&out, (void*)&hb, (void*)&arrive };
  if (use_xe)
    hipLaunchCooperativeKernel(reinterpret_cast<void*>(lstm_main<true>),
                               dim3(GRID_MAIN), dim3(256), args, 0, stream);
  else
    hipLaunchCooperativeKernel(reinterpret_cast<void*>(lstm_main<false>),
                               dim3(GRID_MAIN), dim3(256), args, 0, stream);
}